// Round 12
// baseline (683.027 us; speedup 1.0000x reference)
//
#include <hip/hip_runtime.h>
#include <math.h>

// Problem constants (from reference)
#define N_NODES  50000
#define N_EDGES  800000
#define N_GRAPHS 2500
#define IN_DIM   128
#define HID      128
#define HEADS    2
#define HC       256   // HEADS*HID

typedef unsigned short u16;
typedef unsigned char  u8;
typedef short  s8v  __attribute__((ext_vector_type(8)));   // 8 bf16 = 4 VGPRs (MFMA A/B frag)
typedef float  f4v  __attribute__((ext_vector_type(4)));   // MFMA C/D frag
typedef float  f2v  __attribute__((ext_vector_type(2)));

// bf16 helpers
__device__ inline float bf2f(u16 u) {
    union { unsigned int i; float f; } c; c.i = ((unsigned int)u) << 16; return c.f;
}
__device__ inline u16 f2bf(float x) {
    union { float f; unsigned int i; } c; c.f = x;
    unsigned int r = c.i + 0x7FFFu + ((c.i >> 16) & 1u);
    return (u16)(r >> 16);
}
__device__ inline float bflo(unsigned int u) {
    union { unsigned int i; float f; } c; c.i = u << 16; return c.f;
}
__device__ inline float bfhi(unsigned int u) {
    union { unsigned int i; float f; } c; c.i = u & 0xffff0000u; return c.f;
}

// ---------------------------------------------------------------------------
// fp8 e4m3 encode/decode — HW v_cvt path on gfx950, exact SW fallback
// ---------------------------------------------------------------------------
#if __has_builtin(__builtin_amdgcn_cvt_pk_fp8_f32) && __has_builtin(__builtin_amdgcn_cvt_pk_f32_fp8)
#define FP8_HW 1
#else
#define FP8_HW 0
#endif

__device__ inline u8 f2fp8(float x) {
#if FP8_HW
    return (u8)(__builtin_amdgcn_cvt_pk_fp8_f32(x, x, 0, false) & 0xff);
#else
    union { float f; unsigned int u; } c; c.f = x;
    unsigned int s = (c.u >> 24) & 0x80u;
    c.u &= 0x7fffffffu;
    if (c.f >= 448.f) return (u8)(s | 0x7e);
    if (c.f < 0.015625f) {                        // subnormal: m * 2^-9
        int m = (int)(c.f * 512.f + 0.5f);
        if (m >= 8) return (u8)(s | 0x08);
        return (u8)(s | m);
    }
    c.u += 0x000fffffu + ((c.u >> 20) & 1u);      // RNE at mantissa bit 20
    unsigned int e = ((c.u >> 23) & 0xffu) - 120u;
    unsigned int m = (c.u >> 20) & 7u;
    return (u8)(s | (e << 3) | m);
#endif
}

__device__ inline void fp8x8_to_f32(uint2 kd8, float* kf) {
#if FP8_HW
    f2v p0 = __builtin_amdgcn_cvt_pk_f32_fp8(kd8.x, false);
    f2v p1 = __builtin_amdgcn_cvt_pk_f32_fp8(kd8.x, true);
    f2v p2 = __builtin_amdgcn_cvt_pk_f32_fp8(kd8.y, false);
    f2v p3 = __builtin_amdgcn_cvt_pk_f32_fp8(kd8.y, true);
    kf[0] = p0.x; kf[1] = p0.y; kf[2] = p1.x; kf[3] = p1.y;
    kf[4] = p2.x; kf[5] = p2.y; kf[6] = p3.x; kf[7] = p3.y;
#else
#pragma unroll
    for (int i = 0; i < 8; ++i) {
        unsigned int b = ((i < 4) ? (kd8.x >> (8 * i)) : (kd8.y >> (8 * (i - 4)))) & 0xffu;
        unsigned int em = b & 0x7fu;
        union { unsigned int u; float f; } c;
        c.u = ((b & 0x80u) << 24) | ((em + 960u) << 20);   // normal decode (e+120)
        float fn = c.f;
        float fs = (float)(int)em * 0.001953125f;          // subnorm m*2^-9
        fs = (b & 0x80u) ? -fs : fs;
        kf[i] = (em >= 8u) ? fn : fs;
    }
#endif
}

// ---------------------------------------------------------------------------
// init: blocks 0-48 zero deg, 49-58 zero gdeg, 59/60 int64-autodetect flags
// ---------------------------------------------------------------------------
__global__ __launch_bounds__(256) void init_kernel(
    const int* __restrict__ ei, const int* __restrict__ batch,
    int* __restrict__ deg, int* __restrict__ gdeg,
    int* __restrict__ flag_ei, int* __restrict__ flag_b)
{
    int b = blockIdx.x, t = threadIdx.x;
    if (b < 49) {
        int base = b * 1024 + t * 4;
        if (base + 3 < N_NODES) {
            *(int4*)&deg[base] = make_int4(0, 0, 0, 0);
        } else {
#pragma unroll
            for (int i = 0; i < 4; ++i) if (base + i < N_NODES) deg[base + i] = 0;
        }
    } else if (b < 59) {
        int i = (b - 49) * 256 + t;
        if (i < N_GRAPHS) gdeg[i] = 0;
    } else {
        const int* p = (b == 59) ? ei : batch;
        int ob = (b == 59) ? 1 : 40001;
        int* fl = (b == 59) ? flag_ei : flag_b;
        __shared__ int nz;
        if (t == 0) nz = 0;
        __syncthreads();
        int any = 0;
        for (int i = t; i < 1024; i += 256) if (p[ob + 2 * i] != 0) any = 1;
        if (any) atomicAdd(&nz, 1);
        __syncthreads();
        if (t == 0) *fl = (nz == 0) ? 1 : 0;
    }
}

// ---------------------------------------------------------------------------
// hist (edge dst + batch) AND weight prep in one dispatch (block-ranged)
// ---------------------------------------------------------------------------
#define W1_ELEMS (1024 * 128)
#define W2_ELEMS (896 * 256)
__global__ __launch_bounds__(256) void hist_prep_kernel(
    const int* __restrict__ ei, const int* __restrict__ batch,
    const int* __restrict__ flag_ei, const int* __restrict__ flag_b,
    int* __restrict__ deg, int* __restrict__ gdeg,
    const float* __restrict__ Wq1, const float* __restrict__ Wk1,
    const float* __restrict__ Wv1, const float* __restrict__ Ws1,
    const float* __restrict__ bq1, const float* __restrict__ bk1,
    const float* __restrict__ bv1, const float* __restrict__ bs1,
    const float* __restrict__ Wq2, const float* __restrict__ Wk2,
    const float* __restrict__ Wv2, const float* __restrict__ Ws2,
    const float* __restrict__ bq2, const float* __restrict__ bk2,
    const float* __restrict__ bv2, const float* __restrict__ bs2,
    u16* __restrict__ w1T, float* __restrict__ b1cat,
    u16* __restrict__ w2T, float* __restrict__ b2cat)
{
    const int E = N_EDGES;
    int i = blockIdx.x * 256 + threadIdx.x;
    if (i < E) {
        int f = *flag_ei;
        int d = f ? ei[2 * ((size_t)E + i)] : ei[(size_t)E + i];
        if ((unsigned)d < (unsigned)N_NODES) atomicAdd(&deg[d], 1);
    } else if (i < E + N_NODES) {
        int j = i - E;
        int f = *flag_b;
        int g = f ? batch[2 * (size_t)j] : batch[j];
        if ((unsigned)g < (unsigned)N_GRAPHS) atomicAdd(&gdeg[g], 1);
    } else if (i < E + N_NODES + W1_ELEMS) {
        int t1 = i - E - N_NODES;
        int n = t1 >> 7, k = t1 & 127;
        int w = n >> 8, nc = n & 255;
        const float* W = (w == 0) ? Wq1 : (w == 1) ? Wk1 : (w == 2) ? Wv1 : Ws1;
        w1T[t1] = f2bf(W[k * 256 + nc]);
        if (k == 0) {
            const float* b = (w == 0) ? bq1 : (w == 1) ? bk1 : (w == 2) ? bv1 : bs1;
            b1cat[n] = b[nc];
        }
    } else if (i < E + N_NODES + W1_ELEMS + W2_ELEMS) {
        int t2 = i - E - N_NODES - W1_ELEMS;
        int n = t2 >> 8, k = t2 & 255;
        float val, bval;
        if (n < 768) {
            int w = n >> 8, nc = n & 255;
            const float* W = (w == 0) ? Wq2 : (w == 1) ? Wk2 : Wv2;
            val = W[k * 256 + nc];
            bval = ((w == 0) ? bq2 : (w == 1) ? bk2 : bv2)[nc];
        } else {
            val = Ws2[k * 128 + (n - 768)];
            bval = bs2[n - 768];
        }
        w2T[t2] = f2bf(val);
        if (k == 0) b2cat[n] = bval;
    }
}

// ---------------------------------------------------------------------------
// Parallel scan chain (proven)
// ---------------------------------------------------------------------------
__global__ void scan_local_kernel(const int* __restrict__ deg, int* __restrict__ rowptr,
                                  int* __restrict__ bsums, int n) {
    __shared__ int sh[256];
    int t = threadIdx.x;
    int base = blockIdx.x * 1024 + t * 4;
    int d0 = (base + 0 < n) ? deg[base + 0] : 0;
    int d1 = (base + 1 < n) ? deg[base + 1] : 0;
    int d2 = (base + 2 < n) ? deg[base + 2] : 0;
    int d3 = (base + 3 < n) ? deg[base + 3] : 0;
    sh[t] = d0 + d1 + d2 + d3;
    __syncthreads();
    for (int off = 1; off < 256; off <<= 1) {
        int val = 0;
        if (t >= off) val = sh[t - off];
        __syncthreads();
        if (t >= off) sh[t] += val;
        __syncthreads();
    }
    int excl = (t > 0) ? sh[t - 1] : 0;
    if (t == 255) bsums[blockIdx.x] = sh[255];
    if (base + 0 < n) rowptr[base + 0] = excl;
    if (base + 1 < n) rowptr[base + 1] = excl + d0;
    if (base + 2 < n) rowptr[base + 2] = excl + d0 + d1;
    if (base + 3 < n) rowptr[base + 3] = excl + d0 + d1 + d2;
}

// block 0: wave-scan of <=64 block sums (+ total); block 1: graph scan (2500)
__global__ __launch_bounds__(256) void scan_mid_kernel(
    int* __restrict__ bsums, int nb, int* __restrict__ rowptr_last,
    const int* __restrict__ gdeg, int* __restrict__ growptr)
{
    int t = threadIdx.x;
    if (blockIdx.x == 0) {
        if (t >= 64) return;
        int v = (t < nb) ? bsums[t] : 0;
        int incl = v;
        for (int off = 1; off < 64; off <<= 1) {
            int u = __shfl_up(incl, off);
            if (t >= off) incl += u;
        }
        if (t < nb) bsums[t] = incl - v;
        if (t == 63) *rowptr_last = incl;
    } else {
        __shared__ int sh[256];
        int base = t * 10;
        int loc[10];
        int s = 0;
#pragma unroll
        for (int i = 0; i < 10; ++i) {
            int v = (base + i < N_GRAPHS) ? gdeg[base + i] : 0;
            loc[i] = s; s += v;
        }
        sh[t] = s;
        __syncthreads();
        for (int off = 1; off < 256; off <<= 1) {
            int val = 0;
            if (t >= off) val = sh[t - off];
            __syncthreads();
            if (t >= off) sh[t] += val;
            __syncthreads();
        }
        int excl = (t > 0) ? sh[t - 1] : 0;
#pragma unroll
        for (int i = 0; i < 10; ++i)
            if (base + i < N_GRAPHS) growptr[base + i] = excl + loc[i];
        if (t == 255) growptr[N_GRAPHS] = sh[255];
    }
}

__global__ void scan_add_kernel(int* __restrict__ rowptr, const int* __restrict__ bsums,
                                int* __restrict__ cursor, int n) {
    int i = blockIdx.x * blockDim.x + threadIdx.x;
    if (i < n) {
        int r = rowptr[i] + bsums[i >> 10];
        rowptr[i] = r;
        cursor[i] = r;
    }
}

// ---------------------------------------------------------------------------
// A-slab-resident MFMA GEMM body (BM=64), BARRIER-FREE k-loop:
// B weights (0.25/0.45 MB) are L2-resident — fragments are loaded DIRECTLY
// from global into MFMA registers (no Bs LDS, no k-loop __syncthreads).
// Only one barrier remains (after the A-slab stage), so the compiler can
// pipeline B-loads / ds_reads / MFMAs freely (fix for r9-r11's MfmaUtil<8%
// barrier-serialized k-loop). buf 1 (k tile) written fp8 e4m3, byte-stride 768.
// ---------------------------------------------------------------------------
template <typename AT, int KDIM, int NT>
__device__ __forceinline__ void gemm_slab_body(
    int bx, const AT* __restrict__ A, const u16* __restrict__ BT,
    const float* __restrict__ biascat,
    u16* __restrict__ C0, u8* __restrict__ C1,
    u16* __restrict__ C2, u16* __restrict__ C3,
    int s0, int s2, int s3, int M)
{
    constexpr int AROW = KDIM + 8;
    __shared__ u16 As[64 * AROW];
    int t = threadIdx.x;
    int wid = t >> 6, lane = t & 63;
    int wm = wid >> 1, wn = wid & 1;
    int row0 = bx * 64;

    // ---- stage A slab once ----
    if constexpr (sizeof(AT) == 4) {
#pragma unroll
        for (int i = 0; i < KDIM / 16; ++i) {
            int c = t + i * 256;
            int row = c / (KDIM / 4);
            int kq  = (c % (KDIM / 4)) * 4;
            float4 d = make_float4(0.f, 0.f, 0.f, 0.f);
            if (row0 + row < M)
                d = *(const float4*)&A[(size_t)(row0 + row) * KDIM + kq];
            ushort4 h;
            h.x = f2bf(d.x); h.y = f2bf(d.y); h.z = f2bf(d.z); h.w = f2bf(d.w);
            *(ushort4*)&As[row * AROW + kq] = h;
        }
    } else {
#pragma unroll
        for (int i = 0; i < KDIM / 32; ++i) {
            int c = t + i * 256;
            int row = c / (KDIM / 8);
            int kq  = (c % (KDIM / 8)) * 8;
            uint4 d = make_uint4(0u, 0u, 0u, 0u);
            if (row0 + row < M)
                d = *(const uint4*)&A[(size_t)(row0 + row) * KDIM + kq];
            *(uint4*)&As[row * AROW + kq] = d;
        }
    }
    __syncthreads();     // the ONLY barrier

    int koff = (lane >> 4) * 8;
    int mrow = wm * 32 + (lane & 15);
    int nrowb = wn * 64 + (lane & 15);   // row within the 128-wide n-tile

    for (int nt = 0; nt < NT; ++nt) {
        f4v acc[2][4];
#pragma unroll
        for (int i = 0; i < 2; ++i)
#pragma unroll
            for (int j = 0; j < 4; ++j)
#pragma unroll
                for (int r = 0; r < 4; ++r) acc[i][j][r] = 0.f;

        const u16* Bbase = BT + (size_t)(nt * 128 + nrowb) * KDIM + koff;

#pragma unroll 2
        for (int k0 = 0; k0 < KDIM; k0 += 32) {
            s8v bf[4];
#pragma unroll
            for (int tn = 0; tn < 4; ++tn)
                bf[tn] = *(const s8v*)&Bbase[(size_t)tn * 16 * KDIM + k0];
            s8v af[2];
#pragma unroll
            for (int tm = 0; tm < 2; ++tm)
                af[tm] = *(const s8v*)&As[(mrow + tm * 16) * AROW + k0 + koff];
#pragma unroll
            for (int tm = 0; tm < 2; ++tm)
#pragma unroll
                for (int tn = 0; tn < 4; ++tn)
                    acc[tm][tn] = __builtin_amdgcn_mfma_f32_16x16x32_bf16(
                        af[tm], bf[tn], acc[tm][tn], 0, 0, 0);
        }

        int buf = nt >> 1;
        int colb = (nt & 1) * 128;
        if (buf == 1) {
            // k tile -> fp8 bytes, byte-stride 768
#pragma unroll
            for (int tm = 0; tm < 2; ++tm) {
#pragma unroll
                for (int tn = 0; tn < 4; ++tn) {
                    int colg = nt * 128 + wn * 64 + tn * 16 + (lane & 15);
                    int col  = colb + wn * 64 + tn * 16 + (lane & 15);
                    float b = biascat[colg];
#pragma unroll
                    for (int r = 0; r < 4; ++r) {
                        int row = row0 + wm * 32 + tm * 16 + (lane >> 4) * 4 + r;
                        if (row < M)
                            C1[(size_t)row * 768 + col] = f2fp8(acc[tm][tn][r] + b);
                    }
                }
            }
        } else {
            u16* Cp = (buf == 0) ? C0 : (buf == 2) ? C2 : C3;
            int stride = (buf == 0) ? s0 : (buf == 2) ? s2 : s3;
#pragma unroll
            for (int tm = 0; tm < 2; ++tm) {
#pragma unroll
                for (int tn = 0; tn < 4; ++tn) {
                    int colg = nt * 128 + wn * 64 + tn * 16 + (lane & 15);
                    int col  = colb + wn * 64 + tn * 16 + (lane & 15);
                    float b = biascat[colg];
#pragma unroll
                    for (int r = 0; r < 4; ++r) {
                        int row = row0 + wm * 32 + tm * 16 + (lane >> 4) * 4 + r;
                        if (row < M)
                            Cp[(size_t)row * stride + col] = f2bf(acc[tm][tn][r] + b);
                    }
                }
            }
        }
    }
}

#define GB 782   // ceil(50000/64)

// Layer-1 GEMM with the edge scatter fused in as trailing blocks
__global__ __launch_bounds__(256) void gemm1_scatter_kernel(
    const float* __restrict__ A, const u16* __restrict__ BT,
    const float* __restrict__ biascat,
    u16* __restrict__ C0, u8* __restrict__ C1,
    u16* __restrict__ C2, u16* __restrict__ C3,
    int s0, int s2, int s3, int M,
    const int* __restrict__ ei, const float* __restrict__ ea,
    const int* __restrict__ flag, int* __restrict__ cursor,
    int2* __restrict__ edges)
{
    if (blockIdx.x < GB) {
        gemm_slab_body<float, 128, 8>(blockIdx.x, A, BT, biascat,
                                      C0, C1, C2, C3, s0, s2, s3, M);
    } else {
        const int E = N_EDGES;
        int i = (blockIdx.x - GB) * 256 + threadIdx.x;
        if (i >= E) return;
        int f = *flag;
        int s = f ? ei[2 * (size_t)i] : ei[i];
        int d = f ? ei[2 * ((size_t)E + i)] : ei[(size_t)E + i];
        if ((unsigned)d >= (unsigned)N_NODES) return;
        if ((unsigned)s >= (unsigned)N_NODES) s = 0;
        int p = atomicAdd(&cursor[d], 1);
        int2 rec; rec.x = s; rec.y = __float_as_int(ea[i]);
        edges[p] = rec;
    }
}

__global__ __launch_bounds__(256) void gemm2_kernel(
    const u16* __restrict__ A, const u16* __restrict__ BT,
    const float* __restrict__ biascat,
    u16* __restrict__ C0, u8* __restrict__ C1,
    u16* __restrict__ C2, u16* __restrict__ C3,
    int s0, int s2, int s3, int M)
{
    gemm_slab_body<u16, 256, 7>(blockIdx.x, A, BT, biascat,
                                C0, C1, C2, C3, s0, s2, s3, M);
}

// ---------------------------------------------------------------------------
// Attention: wave per node, 2 edges per step (lane halves), 8 cols/lane.
// KV row (768B): k-fp8[256B] | v-bf16[512B] — one base address per edge.
// Epsilon factoring: alpha = (q.k + ae*(q.We))*scale; v-side folded via pa.
// ---------------------------------------------------------------------------
template <int LAYER>
__global__ __launch_bounds__(256) void attn_node(
    const u16* __restrict__ q, const u8* __restrict__ kv,
    const float* __restrict__ We, const u16* __restrict__ skip,
    const int* __restrict__ rowptr, const int2* __restrict__ edges,
    void* __restrict__ hout, int N)
{
    int wave = (blockIdx.x * blockDim.x + threadIdx.x) >> 6;
    int lane = threadIdx.x & 63;
    if (wave >= N) return;
    int n = wave;
    int half = lane >> 5;
    int cl   = lane & 31;
    const float scale = 0.08838834764831845f;  // 1/sqrt(128)
    const float NEG = -1e30f;

    uint4 qd = *(const uint4*)&q[(size_t)n * HC + cl * 8];
    float qf[8];
    qf[0] = bflo(qd.x); qf[1] = bfhi(qd.x);
    qf[2] = bflo(qd.y); qf[3] = bfhi(qd.y);
    qf[4] = bflo(qd.z); qf[5] = bfhi(qd.z);
    qf[6] = bflo(qd.w); qf[7] = bfhi(qd.w);
    float4 wlo = *(const float4*)&We[cl * 8];
    float4 whi = *(const float4*)&We[cl * 8 + 4];
    float wf[8] = { wlo.x, wlo.y, wlo.z, wlo.w, whi.x, whi.y, whi.z, whi.w };

    float qw = qf[0]*wf[0] + qf[1]*wf[1] + qf[2]*wf[2] + qf[3]*wf[3]
             + qf[4]*wf[4] + qf[5]*wf[5] + qf[6]*wf[6] + qf[7]*wf[7];
    qw += __shfl_xor(qw, 1);
    qw += __shfl_xor(qw, 2);
    qw += __shfl_xor(qw, 4);
    qw += __shfl_xor(qw, 8);

    int e0 = rowptr[n], e1 = rowptr[n + 1];
    float m = NEG, l = 0.f, pa = 0.f;
    float acc[8];
#pragma unroll
    for (int i = 0; i < 8; ++i) acc[i] = 0.f;

    int steps = (e1 - e0 + 1) >> 1;
#pragma unroll 2
    for (int st = 0; st < steps; ++st) {
        int e = e0 + 2 * st + half;
        bool act = (e < e1);
        int idx = act ? e : e0;
        int2 rec = edges[idx];
        int s = rec.x;
        float a_e = __int_as_float(rec.y);
        const u8* base = kv + (size_t)s * 768;
        uint2 kd8 = *(const uint2*)(base + cl * 8);        // 8 fp8 k cols
        uint4 vd  = *(const uint4*)(base + 256 + cl * 16); // 8 bf16 v cols

        float kf[8];
        fp8x8_to_f32(kd8, kf);

        float d = qf[0] * kf[0];
        d = fmaf(qf[1], kf[1], d);
        d = fmaf(qf[2], kf[2], d);
        d = fmaf(qf[3], kf[3], d);
        d = fmaf(qf[4], kf[4], d);
        d = fmaf(qf[5], kf[5], d);
        d = fmaf(qf[6], kf[6], d);
        d = fmaf(qf[7], kf[7], d);
        d += __shfl_xor(d, 1);
        d += __shfl_xor(d, 2);
        d += __shfl_xor(d, 4);
        d += __shfl_xor(d, 8);

        float alpha = act ? fmaf(a_e, qw, d) * scale : NEG;
        float mnew = fmaxf(m, alpha);
        float corr = __expf(m - mnew);
        float p = __expf(alpha - mnew);
        p = act ? p : 0.f;
        l = fmaf(l, corr, p);
        pa = fmaf(pa, corr, p * a_e);
        acc[0] = fmaf(p, bflo(vd.x), acc[0] * corr);
        acc[1] = fmaf(p, bfhi(vd.x), acc[1] * corr);
        acc[2] = fmaf(p, bflo(vd.y), acc[2] * corr);
        acc[3] = fmaf(p, bfhi(vd.y), acc[3] * corr);
        acc[4] = fmaf(p, bflo(vd.z), acc[4] * corr);
        acc[5] = fmaf(p, bfhi(vd.z), acc[5] * corr);
        acc[6] = fmaf(p, bflo(vd.w), acc[6] * corr);
        acc[7] = fmaf(p, bfhi(vd.w), acc[7] * corr);
        m = mnew;
    }

    // merge lane-halves via xor 32
    float mo = __shfl_xor(m, 32);
    float lo = __shfl_xor(l, 32);
    float pao = __shfl_xor(pa, 32);
    float mst = fmaxf(m, mo);
    float cS = __expf(m - mst);
    float cO = __expf(mo - mst);
    l = l * cS + lo * cO;
    pa = pa * cS + pao * cO;
#pragma unroll
    for (int i = 0; i < 8; ++i) {
        float ao = __shfl_xor(acc[i], 32);
        acc[i] = acc[i] * cS + ao * cO;
    }

    float inv = (l > 0.f) ? 1.f / l : 0.f;
    float o[8];
#pragma unroll
    for (int i = 0; i < 8; ++i) o[i] = fmaf(pa, wf[i], acc[i]) * inv;

    if constexpr (LAYER == 1) {
        if (half == 0) {
            uint4 sd = *(const uint4*)&skip[(size_t)n * HC + cl * 8];
            float sf[8];
            sf[0] = bflo(sd.x); sf[1] = bfhi(sd.x);
            sf[2] = bflo(sd.y); sf[3] = bfhi(sd.y);
            sf[4] = bflo(sd.z); sf[5] = bfhi(sd.z);
            sf[6] = bflo(sd.w); sf[7] = bfhi(sd.w);
            ushort4 o4a, o4b;
            o4a.x = f2bf(fmaxf(0.f, o[0] + sf[0]));
            o4a.y = f2bf(fmaxf(0.f, o[1] + sf[1]));
            o4a.z = f2bf(fmaxf(0.f, o[2] + sf[2]));
            o4a.w = f2bf(fmaxf(0.f, o[3] + sf[3]));
            o4b.x = f2bf(fmaxf(0.f, o[4] + sf[4]));
            o4b.y = f2bf(fmaxf(0.f, o[5] + sf[5]));
            o4b.z = f2bf(fmaxf(0.f, o[6] + sf[6]));
            o4b.w = f2bf(fmaxf(0.f, o[7] + sf[7]));
            u16* hp = (u16*)hout + (size_t)n * HC + cl * 8;
            *(ushort4*)hp = o4a;
            *(ushort4*)(hp + 4) = o4b;
        }
    } else {
#pragma unroll
        for (int i = 0; i < 8; ++i) {
            float t2 = __shfl_xor(o[i], 16);
            o[i] = 0.5f * (o[i] + t2);
        }
        if (lane < 16) {
            uint4 sd = *(const uint4*)&skip[(size_t)n * HID + lane * 8];
            float sf[8];
            sf[0] = bflo(sd.x); sf[1] = bfhi(sd.x);
            sf[2] = bflo(sd.y); sf[3] = bfhi(sd.y);
            sf[4] = bflo(sd.z); sf[5] = bfhi(sd.z);
            sf[6] = bflo(sd.w); sf[7] = bfhi(sd.w);
            float* hp = (float*)hout + (size_t)n * HID + lane * 8;
            float4 oa, ob;
            oa.x = o[0] + sf[0]; oa.y = o[1] + sf[1];
            oa.z = o[2] + sf[2]; oa.w = o[3] + sf[3];
            ob.x = o[4] + sf[4]; ob.y = o[5] + sf[5];
            ob.z = o[6] + sf[6]; ob.w = o[7] + sf[7];
            *(float4*)hp = oa;
            *(float4*)(hp + 4) = ob;
        }
    }
}

// ---------------------------------------------------------------------------
// Atomic-free pooling: one wave per graph over dense h2 (batch is sorted)
// ---------------------------------------------------------------------------
__global__ __launch_bounds__(256) void pool_kernel(
    const float* __restrict__ h2, const int* __restrict__ growptr,
    float* __restrict__ out) {
    int wave = (blockIdx.x * blockDim.x + threadIdx.x) >> 6;
    int lane = threadIdx.x & 63;
    if (wave >= N_GRAPHS) return;
    int r0 = growptr[wave], r1 = growptr[wave + 1];
    float sx = 0.f, sy = 0.f;
    for (int r = r0; r < r1; ++r) {
        float2 v = *(const float2*)&h2[(size_t)r * HID + lane * 2];
        sx += v.x; sy += v.y;
    }
    float inv = 1.f / fmaxf((float)(r1 - r0), 1.f);
    float2 o; o.x = sx * inv; o.y = sy * inv;
    *(float2*)&out[(size_t)wave * HID + lane * 2] = o;
}

// ---------------------------------------------------------------------------
// Launch: 10 dispatches. ws ~110 MB. KV row = k-fp8[256B] | v-bf16[512B].
// ---------------------------------------------------------------------------
extern "C" void kernel_launch(void* const* d_in, const int* in_sizes, int n_in,
                              void* d_out, int out_size, void* d_ws, size_t ws_size,
                              hipStream_t stream) {
    const float* x    = (const float*)d_in[0];
    const int*   ei   = (const int*)d_in[1];
    const int*   batch= (const int*)d_in[2];
    const float* ea   = (const float*)d_in[3];
    const float* Wq1  = (const float*)d_in[4];
    const float* bq1  = (const float*)d_in[5];
    const float* Wk1  = (const float*)d_in[6];
    const float* bk1  = (const float*)d_in[7];
    const float* Wv1  = (const float*)d_in[8];
    const float* bv1  = (const float*)d_in[9];
    const float* We1  = (const float*)d_in[10];
    const float* Ws1  = (const float*)d_in[11];
    const float* bs1  = (const float*)d_in[12];
    const float* Wq2  = (const float*)d_in[13];
    const float* bq2  = (const float*)d_in[14];
    const float* Wk2  = (const float*)d_in[15];
    const float* bk2  = (const float*)d_in[16];
    const float* Wv2  = (const float*)d_in[17];
    const float* bv2  = (const float*)d_in[18];
    const float* We2  = (const float*)d_in[19];
    const float* Ws2  = (const float*)d_in[20];
    const float* bs2  = (const float*)d_in[21];
    float* out = (float*)d_out;

    char* ws = (char*)d_ws;
    size_t off = 0;
    auto alloc = [&](size_t bytes) -> void* {
        void* p = ws + off;
        off += (bytes + 255) & ~(size_t)255;
        return p;
    };
    int*   flag_ei = (int*)alloc(4);
    int*   flag_b  = (int*)alloc(4);
    int*   deg     = (int*)alloc((size_t)N_NODES * 4);
    int*   rowptr  = (int*)alloc((size_t)(N_NODES + 1) * 4);
    int*   cursor  = (int*)alloc((size_t)N_NODES * 4);
    int*   bsums   = (int*)alloc(64 * 4);
    int2*  edges   = (int2*)alloc((size_t)N_EDGES * 8);
    int*   gdeg    = (int*)alloc((size_t)N_GRAPHS * 4);
    int*   growptr = (int*)alloc((size_t)(N_GRAPHS + 1) * 4);
    u16*   w1T     = (u16*)alloc((size_t)1024 * 128 * 2);
    float* b1cat   = (float*)alloc(1024 * 4);
    u16*   w2T     = (u16*)alloc((size_t)896 * 256 * 2);
    float* b2cat   = (float*)alloc(896 * 4);
    u16*   B0      = (u16*)alloc((size_t)N_NODES * HC * 2);   // q1 / h1 / h2(fp32 [N,128])
    u16*   B1      = (u16*)alloc((size_t)N_NODES * HC * 2);   // skip1 / q2
    u8*    KVb     = (u8*)alloc((size_t)N_NODES * 768);       // k-fp8 | v-bf16 (both layers)
    u16*   B4      = (u16*)alloc((size_t)N_NODES * HID * 2);  // skip2

    const int E = N_EDGES;

    // 1) zero deg/gdeg + dtype detect
    init_kernel<<<61, 256, 0, stream>>>(ei, batch, deg, gdeg, flag_ei, flag_b);

    // 2) histograms + weight prep
    int hp_grid = (E + N_NODES + W1_ELEMS + W2_ELEMS + 255) / 256;
    hist_prep_kernel<<<hp_grid, 256, 0, stream>>>(
        ei, batch, flag_ei, flag_b, deg, gdeg,
        Wq1, Wk1, Wv1, Ws1, bq1, bk1, bv1, bs1,
        Wq2, Wk2, Wv2, Ws2, bq2, bk2, bv2, bs2,
        w1T, b1cat, w2T, b2cat);

    // 3-5) parallel scan chain
    int nb = (N_NODES + 1023) / 1024;  // 49
    scan_local_kernel<<<nb, 256, 0, stream>>>(deg, rowptr, bsums, N_NODES);
    scan_mid_kernel<<<2, 256, 0, stream>>>(bsums, nb, rowptr + N_NODES, gdeg, growptr);
    scan_add_kernel<<<(N_NODES + 255) / 256, 256, 0, stream>>>(rowptr, bsums, cursor, N_NODES);

    // 6) layer-1 GEMM + edge scatter fused
    //    n-tiles: 0,1->q(B0,256) 2,3->k(KV fp8) 4,5->v(KV+256B, u16 stride 384) 6,7->skip(B1,256)
    int sc_grid = (E + 255) / 256;   // 3125
    gemm1_scatter_kernel<<<GB + sc_grid, 256, 0, stream>>>(
        x, w1T, b1cat, B0, KVb, (u16*)(KVb + 256), B1, 256, 384, 256, N_NODES,
        ei, ea, flag_ei, cursor, edges);

    // 7) attn layer 1: h1 -> B0 (aliases q1; row-local, safe)
    attn_node<1><<<N_NODES / 4, 256, 0, stream>>>(B0, KVb, We1, B1, rowptr, edges, B0, N_NODES);

    // 8) layer-2 GEMM: 0,1->q2(B1) 2,3->k2(fp8) 4,5->v2 6->skip2(B4,128)
    gemm2_kernel<<<GB, 256, 0, stream>>>(
        B0, w2T, b2cat, B1, KVb, (u16*)(KVb + 256), B4, 256, 384, 128, N_NODES);

    // 9) attn layer 2: h2 (fp32 [N,128]) -> B0
    attn_node<2><<<N_NODES / 4, 256, 0, stream>>>(B1, KVb, We2, B4, rowptr, edges, B0, N_NODES);

    // 10) pooling
    pool_kernel<<<(N_GRAPHS + 3) / 4, 256, 0, stream>>>((const float*)B0, growptr, out);
}

// Round 13
// 551.805 us; speedup vs baseline: 1.2378x; 1.2378x over previous
//
#include <hip/hip_runtime.h>
#include <math.h>

// Problem constants (from reference)
#define N_NODES  50000
#define N_EDGES  800000
#define N_GRAPHS 2500
#define IN_DIM   128
#define HID      128
#define HEADS    2
#define HC       256   // HEADS*HID

typedef unsigned short u16;
typedef unsigned char  u8;
typedef short  s8v  __attribute__((ext_vector_type(8)));   // 8 bf16 = 4 VGPRs (MFMA A/B frag)
typedef float  f4v  __attribute__((ext_vector_type(4)));   // MFMA C/D frag
typedef float  f2v  __attribute__((ext_vector_type(2)));

// bf16 helpers
__device__ inline float bf2f(u16 u) {
    union { unsigned int i; float f; } c; c.i = ((unsigned int)u) << 16; return c.f;
}
__device__ inline u16 f2bf(float x) {
    union { float f; unsigned int i; } c; c.f = x;
    unsigned int r = c.i + 0x7FFFu + ((c.i >> 16) & 1u);
    return (u16)(r >> 16);
}
__device__ inline float bflo(unsigned int u) {
    union { unsigned int i; float f; } c; c.i = u << 16; return c.f;
}
__device__ inline float bfhi(unsigned int u) {
    union { unsigned int i; float f; } c; c.i = u & 0xffff0000u; return c.f;
}

// ---------------------------------------------------------------------------
// fp8 e4m3 encode/decode — HW v_cvt path on gfx950, exact SW fallback
// ---------------------------------------------------------------------------
#if __has_builtin(__builtin_amdgcn_cvt_pk_fp8_f32) && __has_builtin(__builtin_amdgcn_cvt_pk_f32_fp8)
#define FP8_HW 1
#else
#define FP8_HW 0
#endif

__device__ inline u8 f2fp8(float x) {
#if FP8_HW
    return (u8)(__builtin_amdgcn_cvt_pk_fp8_f32(x, x, 0, false) & 0xff);
#else
    union { float f; unsigned int u; } c; c.f = x;
    unsigned int s = (c.u >> 24) & 0x80u;
    c.u &= 0x7fffffffu;
    if (c.f >= 448.f) return (u8)(s | 0x7e);
    if (c.f < 0.015625f) {                        // subnormal: m * 2^-9
        int m = (int)(c.f * 512.f + 0.5f);
        if (m >= 8) return (u8)(s | 0x08);
        return (u8)(s | m);
    }
    c.u += 0x000fffffu + ((c.u >> 20) & 1u);      // RNE at mantissa bit 20
    unsigned int e = ((c.u >> 23) & 0xffu) - 120u;
    unsigned int m = (c.u >> 20) & 7u;
    return (u8)(s | (e << 3) | m);
#endif
}

__device__ inline void fp8x8_to_f32(uint2 kd8, float* kf) {
#if FP8_HW
    f2v p0 = __builtin_amdgcn_cvt_pk_f32_fp8(kd8.x, false);
    f2v p1 = __builtin_amdgcn_cvt_pk_f32_fp8(kd8.x, true);
    f2v p2 = __builtin_amdgcn_cvt_pk_f32_fp8(kd8.y, false);
    f2v p3 = __builtin_amdgcn_cvt_pk_f32_fp8(kd8.y, true);
    kf[0] = p0.x; kf[1] = p0.y; kf[2] = p1.x; kf[3] = p1.y;
    kf[4] = p2.x; kf[5] = p2.y; kf[6] = p3.x; kf[7] = p3.y;
#else
#pragma unroll
    for (int i = 0; i < 8; ++i) {
        unsigned int b = ((i < 4) ? (kd8.x >> (8 * i)) : (kd8.y >> (8 * (i - 4)))) & 0xffu;
        unsigned int em = b & 0x7fu;
        union { unsigned int u; float f; } c;
        c.u = ((b & 0x80u) << 24) | ((em + 960u) << 20);   // normal decode (e+120)
        float fn = c.f;
        float fs = (float)(int)em * 0.001953125f;          // subnorm m*2^-9
        fs = (b & 0x80u) ? -fs : fs;
        kf[i] = (em >= 8u) ? fn : fs;
    }
#endif
}

// ---------------------------------------------------------------------------
// init: blocks 0-48 zero deg, 49-58 zero gdeg, 59/60 int64-autodetect flags
// ---------------------------------------------------------------------------
__global__ __launch_bounds__(256) void init_kernel(
    const int* __restrict__ ei, const int* __restrict__ batch,
    int* __restrict__ deg, int* __restrict__ gdeg,
    int* __restrict__ flag_ei, int* __restrict__ flag_b)
{
    int b = blockIdx.x, t = threadIdx.x;
    if (b < 49) {
        int base = b * 1024 + t * 4;
        if (base + 3 < N_NODES) {
            *(int4*)&deg[base] = make_int4(0, 0, 0, 0);
        } else {
#pragma unroll
            for (int i = 0; i < 4; ++i) if (base + i < N_NODES) deg[base + i] = 0;
        }
    } else if (b < 59) {
        int i = (b - 49) * 256 + t;
        if (i < N_GRAPHS) gdeg[i] = 0;
    } else {
        const int* p = (b == 59) ? ei : batch;
        int ob = (b == 59) ? 1 : 40001;
        int* fl = (b == 59) ? flag_ei : flag_b;
        __shared__ int nz;
        if (t == 0) nz = 0;
        __syncthreads();
        int any = 0;
        for (int i = t; i < 1024; i += 256) if (p[ob + 2 * i] != 0) any = 1;
        if (any) atomicAdd(&nz, 1);
        __syncthreads();
        if (t == 0) *fl = (nz == 0) ? 1 : 0;
    }
}

// ---------------------------------------------------------------------------
// hist (edge dst + batch) AND weight prep in one dispatch (block-ranged)
// ---------------------------------------------------------------------------
#define W1_ELEMS (1024 * 128)
#define W2_ELEMS (896 * 256)
__global__ __launch_bounds__(256) void hist_prep_kernel(
    const int* __restrict__ ei, const int* __restrict__ batch,
    const int* __restrict__ flag_ei, const int* __restrict__ flag_b,
    int* __restrict__ deg, int* __restrict__ gdeg,
    const float* __restrict__ Wq1, const float* __restrict__ Wk1,
    const float* __restrict__ Wv1, const float* __restrict__ Ws1,
    const float* __restrict__ bq1, const float* __restrict__ bk1,
    const float* __restrict__ bv1, const float* __restrict__ bs1,
    const float* __restrict__ Wq2, const float* __restrict__ Wk2,
    const float* __restrict__ Wv2, const float* __restrict__ Ws2,
    const float* __restrict__ bq2, const float* __restrict__ bk2,
    const float* __restrict__ bv2, const float* __restrict__ bs2,
    u16* __restrict__ w1T, float* __restrict__ b1cat,
    u16* __restrict__ w2T, float* __restrict__ b2cat)
{
    const int E = N_EDGES;
    int i = blockIdx.x * 256 + threadIdx.x;
    if (i < E) {
        int f = *flag_ei;
        int d = f ? ei[2 * ((size_t)E + i)] : ei[(size_t)E + i];
        if ((unsigned)d < (unsigned)N_NODES) atomicAdd(&deg[d], 1);
    } else if (i < E + N_NODES) {
        int j = i - E;
        int f = *flag_b;
        int g = f ? batch[2 * (size_t)j] : batch[j];
        if ((unsigned)g < (unsigned)N_GRAPHS) atomicAdd(&gdeg[g], 1);
    } else if (i < E + N_NODES + W1_ELEMS) {
        int t1 = i - E - N_NODES;
        int n = t1 >> 7, k = t1 & 127;
        int w = n >> 8, nc = n & 255;
        const float* W = (w == 0) ? Wq1 : (w == 1) ? Wk1 : (w == 2) ? Wv1 : Ws1;
        w1T[t1] = f2bf(W[k * 256 + nc]);
        if (k == 0) {
            const float* b = (w == 0) ? bq1 : (w == 1) ? bk1 : (w == 2) ? bv1 : bs1;
            b1cat[n] = b[nc];
        }
    } else if (i < E + N_NODES + W1_ELEMS + W2_ELEMS) {
        int t2 = i - E - N_NODES - W1_ELEMS;
        int n = t2 >> 8, k = t2 & 255;
        float val, bval;
        if (n < 768) {
            int w = n >> 8, nc = n & 255;
            const float* W = (w == 0) ? Wq2 : (w == 1) ? Wk2 : Wv2;
            val = W[k * 256 + nc];
            bval = ((w == 0) ? bq2 : (w == 1) ? bk2 : bv2)[nc];
        } else {
            val = Ws2[k * 128 + (n - 768)];
            bval = bs2[n - 768];
        }
        w2T[t2] = f2bf(val);
        if (k == 0) b2cat[n] = bval;
    }
}

// ---------------------------------------------------------------------------
// Parallel scan chain (proven)
// ---------------------------------------------------------------------------
__global__ void scan_local_kernel(const int* __restrict__ deg, int* __restrict__ rowptr,
                                  int* __restrict__ bsums, int n) {
    __shared__ int sh[256];
    int t = threadIdx.x;
    int base = blockIdx.x * 1024 + t * 4;
    int d0 = (base + 0 < n) ? deg[base + 0] : 0;
    int d1 = (base + 1 < n) ? deg[base + 1] : 0;
    int d2 = (base + 2 < n) ? deg[base + 2] : 0;
    int d3 = (base + 3 < n) ? deg[base + 3] : 0;
    sh[t] = d0 + d1 + d2 + d3;
    __syncthreads();
    for (int off = 1; off < 256; off <<= 1) {
        int val = 0;
        if (t >= off) val = sh[t - off];
        __syncthreads();
        if (t >= off) sh[t] += val;
        __syncthreads();
    }
    int excl = (t > 0) ? sh[t - 1] : 0;
    if (t == 255) bsums[blockIdx.x] = sh[255];
    if (base + 0 < n) rowptr[base + 0] = excl;
    if (base + 1 < n) rowptr[base + 1] = excl + d0;
    if (base + 2 < n) rowptr[base + 2] = excl + d0 + d1;
    if (base + 3 < n) rowptr[base + 3] = excl + d0 + d1 + d2;
}

// block 0: wave-scan of <=64 block sums (+ total); block 1: graph scan (2500)
__global__ __launch_bounds__(256) void scan_mid_kernel(
    int* __restrict__ bsums, int nb, int* __restrict__ rowptr_last,
    const int* __restrict__ gdeg, int* __restrict__ growptr)
{
    int t = threadIdx.x;
    if (blockIdx.x == 0) {
        if (t >= 64) return;
        int v = (t < nb) ? bsums[t] : 0;
        int incl = v;
        for (int off = 1; off < 64; off <<= 1) {
            int u = __shfl_up(incl, off);
            if (t >= off) incl += u;
        }
        if (t < nb) bsums[t] = incl - v;
        if (t == 63) *rowptr_last = incl;
    } else {
        __shared__ int sh[256];
        int base = t * 10;
        int loc[10];
        int s = 0;
#pragma unroll
        for (int i = 0; i < 10; ++i) {
            int v = (base + i < N_GRAPHS) ? gdeg[base + i] : 0;
            loc[i] = s; s += v;
        }
        sh[t] = s;
        __syncthreads();
        for (int off = 1; off < 256; off <<= 1) {
            int val = 0;
            if (t >= off) val = sh[t - off];
            __syncthreads();
            if (t >= off) sh[t] += val;
            __syncthreads();
        }
        int excl = (t > 0) ? sh[t - 1] : 0;
#pragma unroll
        for (int i = 0; i < 10; ++i)
            if (base + i < N_GRAPHS) growptr[base + i] = excl + loc[i];
        if (t == 255) growptr[N_GRAPHS] = sh[255];
    }
}

__global__ void scan_add_kernel(int* __restrict__ rowptr, const int* __restrict__ bsums,
                                int* __restrict__ cursor, int n) {
    int i = blockIdx.x * blockDim.x + threadIdx.x;
    if (i < n) {
        int r = rowptr[i] + bsums[i >> 10];
        rowptr[i] = r;
        cursor[i] = r;
    }
}

// ---------------------------------------------------------------------------
// A-slab-resident MFMA GEMM body (BM=64). Proven r9 structure: BK=32,
// LDS-staged B tile, simple 2-barrier k-loop. (r10 pipelined BK=64, r11
// n-tile split, r12 barrier-free direct-global-B ALL regressed vs this.)
// buf 1 (k tile) is written fp8 e4m3 at byte-stride 768
// (KV row = k-fp8[256B] | v-bf16[512B]).
// ---------------------------------------------------------------------------
template <typename AT, int KDIM, int NT>
__device__ __forceinline__ void gemm_slab_body(
    int bx, const AT* __restrict__ A, const u16* __restrict__ BT,
    const float* __restrict__ biascat,
    u16* __restrict__ C0, u8* __restrict__ C1,
    u16* __restrict__ C2, u16* __restrict__ C3,
    int s0, int s2, int s3, int M)
{
    constexpr int AROW = KDIM + 8;
    __shared__ u16 As[64 * AROW];
    __shared__ u16 Bs[128 * 40];
    int t = threadIdx.x;
    int wid = t >> 6, lane = t & 63;
    int wm = wid >> 1, wn = wid & 1;
    int row0 = bx * 64;

    if constexpr (sizeof(AT) == 4) {
#pragma unroll
        for (int i = 0; i < KDIM / 16; ++i) {
            int c = t + i * 256;
            int row = c / (KDIM / 4);
            int kq  = (c % (KDIM / 4)) * 4;
            float4 d = make_float4(0.f, 0.f, 0.f, 0.f);
            if (row0 + row < M)
                d = *(const float4*)&A[(size_t)(row0 + row) * KDIM + kq];
            ushort4 h;
            h.x = f2bf(d.x); h.y = f2bf(d.y); h.z = f2bf(d.z); h.w = f2bf(d.w);
            *(ushort4*)&As[row * AROW + kq] = h;
        }
    } else {
#pragma unroll
        for (int i = 0; i < KDIM / 32; ++i) {
            int c = t + i * 256;
            int row = c / (KDIM / 8);
            int kq  = (c % (KDIM / 8)) * 8;
            uint4 d = make_uint4(0u, 0u, 0u, 0u);
            if (row0 + row < M)
                d = *(const uint4*)&A[(size_t)(row0 + row) * KDIM + kq];
            *(uint4*)&As[row * AROW + kq] = d;
        }
    }
    __syncthreads();

    int koff = (lane >> 4) * 8;
    int mrow = wm * 32 + (lane & 15);
    int nrow = wn * 64 + (lane & 15);

    for (int nt = 0; nt < NT; ++nt) {
        f4v acc[2][4];
#pragma unroll
        for (int i = 0; i < 2; ++i)
#pragma unroll
            for (int j = 0; j < 4; ++j)
#pragma unroll
                for (int r = 0; r < 4; ++r) acc[i][j][r] = 0.f;

        for (int k0 = 0; k0 < KDIM; k0 += 32) {
#pragma unroll
            for (int i = 0; i < 2; ++i) {
                int c = t + i * 256;
                int brow = c >> 2, kq = (c & 3) * 8;
                *(uint4*)&Bs[brow * 40 + kq] =
                    *(const uint4*)&BT[(size_t)(nt * 128 + brow) * KDIM + k0 + kq];
            }
            __syncthreads();
            s8v af[2], bf[4];
#pragma unroll
            for (int tm = 0; tm < 2; ++tm)
                af[tm] = *(const s8v*)&As[(mrow + tm * 16) * AROW + k0 + koff];
#pragma unroll
            for (int tn = 0; tn < 4; ++tn)
                bf[tn] = *(const s8v*)&Bs[(nrow + tn * 16) * 40 + koff];
#pragma unroll
            for (int tm = 0; tm < 2; ++tm)
#pragma unroll
                for (int tn = 0; tn < 4; ++tn)
                    acc[tm][tn] = __builtin_amdgcn_mfma_f32_16x16x32_bf16(
                        af[tm], bf[tn], acc[tm][tn], 0, 0, 0);
            __syncthreads();
        }

        int buf = nt >> 1;
        int colb = (nt & 1) * 128;
        if (buf == 1) {
            // k tile -> fp8 bytes, byte-stride 768
#pragma unroll
            for (int tm = 0; tm < 2; ++tm) {
#pragma unroll
                for (int tn = 0; tn < 4; ++tn) {
                    int colg = nt * 128 + wn * 64 + tn * 16 + (lane & 15);
                    int col  = colb + wn * 64 + tn * 16 + (lane & 15);
                    float b = biascat[colg];
#pragma unroll
                    for (int r = 0; r < 4; ++r) {
                        int row = row0 + wm * 32 + tm * 16 + (lane >> 4) * 4 + r;
                        if (row < M)
                            C1[(size_t)row * 768 + col] = f2fp8(acc[tm][tn][r] + b);
                    }
                }
            }
        } else {
            u16* Cp = (buf == 0) ? C0 : (buf == 2) ? C2 : C3;
            int stride = (buf == 0) ? s0 : (buf == 2) ? s2 : s3;
#pragma unroll
            for (int tm = 0; tm < 2; ++tm) {
#pragma unroll
                for (int tn = 0; tn < 4; ++tn) {
                    int colg = nt * 128 + wn * 64 + tn * 16 + (lane & 15);
                    int col  = colb + wn * 64 + tn * 16 + (lane & 15);
                    float b = biascat[colg];
#pragma unroll
                    for (int r = 0; r < 4; ++r) {
                        int row = row0 + wm * 32 + tm * 16 + (lane >> 4) * 4 + r;
                        if (row < M)
                            Cp[(size_t)row * stride + col] = f2bf(acc[tm][tn][r] + b);
                    }
                }
            }
        }
    }
}

#define GB 782   // ceil(50000/64)

// Layer-1 GEMM with the edge scatter fused in as trailing blocks
__global__ __launch_bounds__(256) void gemm1_scatter_kernel(
    const float* __restrict__ A, const u16* __restrict__ BT,
    const float* __restrict__ biascat,
    u16* __restrict__ C0, u8* __restrict__ C1,
    u16* __restrict__ C2, u16* __restrict__ C3,
    int s0, int s2, int s3, int M,
    const int* __restrict__ ei, const float* __restrict__ ea,
    const int* __restrict__ flag, int* __restrict__ cursor,
    int2* __restrict__ edges)
{
    if (blockIdx.x < GB) {
        gemm_slab_body<float, 128, 8>(blockIdx.x, A, BT, biascat,
                                      C0, C1, C2, C3, s0, s2, s3, M);
    } else {
        const int E = N_EDGES;
        int i = (blockIdx.x - GB) * 256 + threadIdx.x;
        if (i >= E) return;
        int f = *flag;
        int s = f ? ei[2 * (size_t)i] : ei[i];
        int d = f ? ei[2 * ((size_t)E + i)] : ei[(size_t)E + i];
        if ((unsigned)d >= (unsigned)N_NODES) return;
        if ((unsigned)s >= (unsigned)N_NODES) s = 0;
        int p = atomicAdd(&cursor[d], 1);
        int2 rec; rec.x = s; rec.y = __float_as_int(ea[i]);
        edges[p] = rec;
    }
}

__global__ __launch_bounds__(256) void gemm2_kernel(
    const u16* __restrict__ A, const u16* __restrict__ BT,
    const float* __restrict__ biascat,
    u16* __restrict__ C0, u8* __restrict__ C1,
    u16* __restrict__ C2, u16* __restrict__ C3,
    int s0, int s2, int s3, int M)
{
    gemm_slab_body<u16, 256, 7>(blockIdx.x, A, BT, biascat,
                                C0, C1, C2, C3, s0, s2, s3, M);
}

// ---------------------------------------------------------------------------
// Attention: wave per node, 2 edges per step (lane halves), 8 cols/lane.
// KV row (768B): k-fp8[256B] | v-bf16[512B] — one base address per edge.
// Epsilon factoring: alpha = (q.k + ae*(q.We))*scale; v-side folded via pa.
// ---------------------------------------------------------------------------
template <int LAYER>
__global__ __launch_bounds__(256) void attn_node(
    const u16* __restrict__ q, const u8* __restrict__ kv,
    const float* __restrict__ We, const u16* __restrict__ skip,
    const int* __restrict__ rowptr, const int2* __restrict__ edges,
    void* __restrict__ hout, int N)
{
    int wave = (blockIdx.x * blockDim.x + threadIdx.x) >> 6;
    int lane = threadIdx.x & 63;
    if (wave >= N) return;
    int n = wave;
    int half = lane >> 5;
    int cl   = lane & 31;
    const float scale = 0.08838834764831845f;  // 1/sqrt(128)
    const float NEG = -1e30f;

    uint4 qd = *(const uint4*)&q[(size_t)n * HC + cl * 8];
    float qf[8];
    qf[0] = bflo(qd.x); qf[1] = bfhi(qd.x);
    qf[2] = bflo(qd.y); qf[3] = bfhi(qd.y);
    qf[4] = bflo(qd.z); qf[5] = bfhi(qd.z);
    qf[6] = bflo(qd.w); qf[7] = bfhi(qd.w);
    float4 wlo = *(const float4*)&We[cl * 8];
    float4 whi = *(const float4*)&We[cl * 8 + 4];
    float wf[8] = { wlo.x, wlo.y, wlo.z, wlo.w, whi.x, whi.y, whi.z, whi.w };

    float qw = qf[0]*wf[0] + qf[1]*wf[1] + qf[2]*wf[2] + qf[3]*wf[3]
             + qf[4]*wf[4] + qf[5]*wf[5] + qf[6]*wf[6] + qf[7]*wf[7];
    qw += __shfl_xor(qw, 1);
    qw += __shfl_xor(qw, 2);
    qw += __shfl_xor(qw, 4);
    qw += __shfl_xor(qw, 8);

    int e0 = rowptr[n], e1 = rowptr[n + 1];
    float m = NEG, l = 0.f, pa = 0.f;
    float acc[8];
#pragma unroll
    for (int i = 0; i < 8; ++i) acc[i] = 0.f;

    int steps = (e1 - e0 + 1) >> 1;
#pragma unroll 2
    for (int st = 0; st < steps; ++st) {
        int e = e0 + 2 * st + half;
        bool act = (e < e1);
        int idx = act ? e : e0;
        int2 rec = edges[idx];
        int s = rec.x;
        float a_e = __int_as_float(rec.y);
        const u8* base = kv + (size_t)s * 768;
        uint2 kd8 = *(const uint2*)(base + cl * 8);        // 8 fp8 k cols
        uint4 vd  = *(const uint4*)(base + 256 + cl * 16); // 8 bf16 v cols

        float kf[8];
        fp8x8_to_f32(kd8, kf);

        float d = qf[0] * kf[0];
        d = fmaf(qf[1], kf[1], d);
        d = fmaf(qf[2], kf[2], d);
        d = fmaf(qf[3], kf[3], d);
        d = fmaf(qf[4], kf[4], d);
        d = fmaf(qf[5], kf[5], d);
        d = fmaf(qf[6], kf[6], d);
        d = fmaf(qf[7], kf[7], d);
        d += __shfl_xor(d, 1);
        d += __shfl_xor(d, 2);
        d += __shfl_xor(d, 4);
        d += __shfl_xor(d, 8);

        float alpha = act ? fmaf(a_e, qw, d) * scale : NEG;
        float mnew = fmaxf(m, alpha);
        float corr = __expf(m - mnew);
        float p = __expf(alpha - mnew);
        p = act ? p : 0.f;
        l = fmaf(l, corr, p);
        pa = fmaf(pa, corr, p * a_e);
        acc[0] = fmaf(p, bflo(vd.x), acc[0] * corr);
        acc[1] = fmaf(p, bfhi(vd.x), acc[1] * corr);
        acc[2] = fmaf(p, bflo(vd.y), acc[2] * corr);
        acc[3] = fmaf(p, bfhi(vd.y), acc[3] * corr);
        acc[4] = fmaf(p, bflo(vd.z), acc[4] * corr);
        acc[5] = fmaf(p, bfhi(vd.z), acc[5] * corr);
        acc[6] = fmaf(p, bflo(vd.w), acc[6] * corr);
        acc[7] = fmaf(p, bfhi(vd.w), acc[7] * corr);
        m = mnew;
    }

    // merge lane-halves via xor 32
    float mo = __shfl_xor(m, 32);
    float lo = __shfl_xor(l, 32);
    float pao = __shfl_xor(pa, 32);
    float mst = fmaxf(m, mo);
    float cS = __expf(m - mst);
    float cO = __expf(mo - mst);
    l = l * cS + lo * cO;
    pa = pa * cS + pao * cO;
#pragma unroll
    for (int i = 0; i < 8; ++i) {
        float ao = __shfl_xor(acc[i], 32);
        acc[i] = acc[i] * cS + ao * cO;
    }

    float inv = (l > 0.f) ? 1.f / l : 0.f;
    float o[8];
#pragma unroll
    for (int i = 0; i < 8; ++i) o[i] = fmaf(pa, wf[i], acc[i]) * inv;

    if constexpr (LAYER == 1) {
        if (half == 0) {
            uint4 sd = *(const uint4*)&skip[(size_t)n * HC + cl * 8];
            float sf[8];
            sf[0] = bflo(sd.x); sf[1] = bfhi(sd.x);
            sf[2] = bflo(sd.y); sf[3] = bfhi(sd.y);
            sf[4] = bflo(sd.z); sf[5] = bfhi(sd.z);
            sf[6] = bflo(sd.w); sf[7] = bfhi(sd.w);
            ushort4 o4a, o4b;
            o4a.x = f2bf(fmaxf(0.f, o[0] + sf[0]));
            o4a.y = f2bf(fmaxf(0.f, o[1] + sf[1]));
            o4a.z = f2bf(fmaxf(0.f, o[2] + sf[2]));
            o4a.w = f2bf(fmaxf(0.f, o[3] + sf[3]));
            o4b.x = f2bf(fmaxf(0.f, o[4] + sf[4]));
            o4b.y = f2bf(fmaxf(0.f, o[5] + sf[5]));
            o4b.z = f2bf(fmaxf(0.f, o[6] + sf[6]));
            o4b.w = f2bf(fmaxf(0.f, o[7] + sf[7]));
            u16* hp = (u16*)hout + (size_t)n * HC + cl * 8;
            *(ushort4*)hp = o4a;
            *(ushort4*)(hp + 4) = o4b;
        }
    } else {
#pragma unroll
        for (int i = 0; i < 8; ++i) {
            float t2 = __shfl_xor(o[i], 16);
            o[i] = 0.5f * (o[i] + t2);
        }
        if (lane < 16) {
            uint4 sd = *(const uint4*)&skip[(size_t)n * HID + lane * 8];
            float sf[8];
            sf[0] = bflo(sd.x); sf[1] = bfhi(sd.x);
            sf[2] = bflo(sd.y); sf[3] = bfhi(sd.y);
            sf[4] = bflo(sd.z); sf[5] = bfhi(sd.z);
            sf[6] = bflo(sd.w); sf[7] = bfhi(sd.w);
            float* hp = (float*)hout + (size_t)n * HID + lane * 8;
            float4 oa, ob;
            oa.x = o[0] + sf[0]; oa.y = o[1] + sf[1];
            oa.z = o[2] + sf[2]; oa.w = o[3] + sf[3];
            ob.x = o[4] + sf[4]; ob.y = o[5] + sf[5];
            ob.z = o[6] + sf[6]; ob.w = o[7] + sf[7];
            *(float4*)hp = oa;
            *(float4*)(hp + 4) = ob;
        }
    }
}

// ---------------------------------------------------------------------------
// Atomic-free pooling: one wave per graph over dense h2 (batch is sorted)
// ---------------------------------------------------------------------------
__global__ __launch_bounds__(256) void pool_kernel(
    const float* __restrict__ h2, const int* __restrict__ growptr,
    float* __restrict__ out) {
    int wave = (blockIdx.x * blockDim.x + threadIdx.x) >> 6;
    int lane = threadIdx.x & 63;
    if (wave >= N_GRAPHS) return;
    int r0 = growptr[wave], r1 = growptr[wave + 1];
    float sx = 0.f, sy = 0.f;
    for (int r = r0; r < r1; ++r) {
        float2 v = *(const float2*)&h2[(size_t)r * HID + lane * 2];
        sx += v.x; sy += v.y;
    }
    float inv = 1.f / fmaxf((float)(r1 - r0), 1.f);
    float2 o; o.x = sx * inv; o.y = sy * inv;
    *(float2*)&out[(size_t)wave * HID + lane * 2] = o;
}

// ---------------------------------------------------------------------------
// Launch: 10 dispatches. ws ~110 MB. KV row = k-fp8[256B] | v-bf16[512B].
// ---------------------------------------------------------------------------
extern "C" void kernel_launch(void* const* d_in, const int* in_sizes, int n_in,
                              void* d_out, int out_size, void* d_ws, size_t ws_size,
                              hipStream_t stream) {
    const float* x    = (const float*)d_in[0];
    const int*   ei   = (const int*)d_in[1];
    const int*   batch= (const int*)d_in[2];
    const float* ea   = (const float*)d_in[3];
    const float* Wq1  = (const float*)d_in[4];
    const float* bq1  = (const float*)d_in[5];
    const float* Wk1  = (const float*)d_in[6];
    const float* bk1  = (const float*)d_in[7];
    const float* Wv1  = (const float*)d_in[8];
    const float* bv1  = (const float*)d_in[9];
    const float* We1  = (const float*)d_in[10];
    const float* Ws1  = (const float*)d_in[11];
    const float* bs1  = (const float*)d_in[12];
    const float* Wq2  = (const float*)d_in[13];
    const float* bq2  = (const float*)d_in[14];
    const float* Wk2  = (const float*)d_in[15];
    const float* bk2  = (const float*)d_in[16];
    const float* Wv2  = (const float*)d_in[17];
    const float* bv2  = (const float*)d_in[18];
    const float* We2  = (const float*)d_in[19];
    const float* Ws2  = (const float*)d_in[20];
    const float* bs2  = (const float*)d_in[21];
    float* out = (float*)d_out;

    char* ws = (char*)d_ws;
    size_t off = 0;
    auto alloc = [&](size_t bytes) -> void* {
        void* p = ws + off;
        off += (bytes + 255) & ~(size_t)255;
        return p;
    };
    int*   flag_ei = (int*)alloc(4);
    int*   flag_b  = (int*)alloc(4);
    int*   deg     = (int*)alloc((size_t)N_NODES * 4);
    int*   rowptr  = (int*)alloc((size_t)(N_NODES + 1) * 4);
    int*   cursor  = (int*)alloc((size_t)N_NODES * 4);
    int*   bsums   = (int*)alloc(64 * 4);
    int2*  edges   = (int2*)alloc((size_t)N_EDGES * 8);
    int*   gdeg    = (int*)alloc((size_t)N_GRAPHS * 4);
    int*   growptr = (int*)alloc((size_t)(N_GRAPHS + 1) * 4);
    u16*   w1T     = (u16*)alloc((size_t)1024 * 128 * 2);
    float* b1cat   = (float*)alloc(1024 * 4);
    u16*   w2T     = (u16*)alloc((size_t)896 * 256 * 2);
    float* b2cat   = (float*)alloc(896 * 4);
    u16*   B0      = (u16*)alloc((size_t)N_NODES * HC * 2);   // q1 / h1 / h2(fp32 [N,128])
    u16*   B1      = (u16*)alloc((size_t)N_NODES * HC * 2);   // skip1 / q2
    u8*    KVb     = (u8*)alloc((size_t)N_NODES * 768);       // k-fp8 | v-bf16 (both layers)
    u16*   B4      = (u16*)alloc((size_t)N_NODES * HID * 2);  // skip2

    const int E = N_EDGES;

    // 1) zero deg/gdeg + dtype detect
    init_kernel<<<61, 256, 0, stream>>>(ei, batch, deg, gdeg, flag_ei, flag_b);

    // 2) histograms + weight prep
    int hp_grid = (E + N_NODES + W1_ELEMS + W2_ELEMS + 255) / 256;
    hist_prep_kernel<<<hp_grid, 256, 0, stream>>>(
        ei, batch, flag_ei, flag_b, deg, gdeg,
        Wq1, Wk1, Wv1, Ws1, bq1, bk1, bv1, bs1,
        Wq2, Wk2, Wv2, Ws2, bq2, bk2, bv2, bs2,
        w1T, b1cat, w2T, b2cat);

    // 3-5) parallel scan chain
    int nb = (N_NODES + 1023) / 1024;  // 49
    scan_local_kernel<<<nb, 256, 0, stream>>>(deg, rowptr, bsums, N_NODES);
    scan_mid_kernel<<<2, 256, 0, stream>>>(bsums, nb, rowptr + N_NODES, gdeg, growptr);
    scan_add_kernel<<<(N_NODES + 255) / 256, 256, 0, stream>>>(rowptr, bsums, cursor, N_NODES);

    // 6) layer-1 GEMM + edge scatter fused
    //    n-tiles: 0,1->q(B0,256) 2,3->k(KV fp8) 4,5->v(KV+256B, u16 stride 384) 6,7->skip(B1,256)
    int sc_grid = (E + 255) / 256;   // 3125
    gemm1_scatter_kernel<<<GB + sc_grid, 256, 0, stream>>>(
        x, w1T, b1cat, B0, KVb, (u16*)(KVb + 256), B1, 256, 384, 256, N_NODES,
        ei, ea, flag_ei, cursor, edges);

    // 7) attn layer 1: h1 -> B0 (aliases q1; row-local, safe)
    attn_node<1><<<N_NODES / 4, 256, 0, stream>>>(B0, KVb, We1, B1, rowptr, edges, B0, N_NODES);

    // 8) layer-2 GEMM: 0,1->q2(B1) 2,3->k2(fp8) 4,5->v2 6->skip2(B4,128)
    gemm2_kernel<<<GB, 256, 0, stream>>>(
        B0, w2T, b2cat, B1, KVb, (u16*)(KVb + 256), B4, 256, 384, 128, N_NODES);

    // 9) attn layer 2: h2 (fp32 [N,128]) -> B0
    attn_node<2><<<N_NODES / 4, 256, 0, stream>>>(B1, KVb, We2, B4, rowptr, edges, B0, N_NODES);

    // 10) pooling
    pool_kernel<<<(N_GRAPHS + 3) / 4, 256, 0, stream>>>((const float*)B0, growptr, out);
}